// Round 8
// baseline (59.737 us; speedup 1.0000x reference)
//
#include <hip/hip_runtime.h>
#include <math.h>

// STDP_84791244358141 — T=256, N=1024, AP=AN=1, TP=TN=2, TE=1. fp32 in/out.
//
// MATH (verified r5/r6, absmax 0.0 exact vs np ref before reassociation):
// te=1 kills the e-carry; output is the last step's outer product only:
//     e[i][j] = x_T[i]*q_T[j] - p_T[i]*y_T[j],  x_t = x + (p-x)/2 etc.
//
// R7 POST-MORTEM: traces fixed (102 -> <5 us). Remaining controllable cost
// is WORKGROUP DISPATCH: outer had 1024 tiny blocks (one float4 store per
// thread) -> ~12-15 us dispatch-bound (r6 residual shows outer+overhead
// ~19 us while its store BW is worth ~1 us). This round: outer = 128 blocks
// x 8 rows (128 B stored/thread); traces = 16 segments x batch-16 loads
// (single vmcnt drain, 128 blocks). Segment partials combine exactly via
// pow2 scaling (ldexpf); reassociation error ~5e-4 << 9.9e-3 threshold.

constexpr int BLOCK = 256;

// Traces, tuned: T%16==0, T/16<=16, N%16==0. Block = 16 segs x 16 cols.
// Grid = 2*(N/16). ws: [0,N)=x_T, [N,2N)=y_T, [2N,3N)=p_T, [3N,4N)=q_T.
__global__ __launch_bounds__(BLOCK) void stdp_traces16(
    const float* __restrict__ pre, const float* __restrict__ post,
    float* __restrict__ ws, int N, int T)
{
    const int tid = threadIdx.x;
    const int seg = tid >> 4;                 // 0..15
    const int cof = tid & 15;
    const int b   = blockIdx.x;
    const int ngroups = N >> 4;
    const int tensor  = (b >= ngroups) ? 1 : 0;
    const int colbase = (tensor ? b - ngroups : b) << 4;
    const int col     = colbase + cof;
    const float* __restrict__ src = tensor ? post : pre;

    const int L  = T >> 4;                    // 16 for T=256
    const int t0 = seg * L;

    float tmp[16];
#pragma unroll
    for (int k = 0; k < 16; ++k)              // all L loads independent
        if (k < L) tmp[k] = src[(size_t)(t0 + k) * N + col];
    float v = 0.0f;
#pragma unroll
    for (int k = 0; k < 16; ++k)
        if (k < L) v += (tmp[k] - v) * 0.5f;  // reference rounding sequence

    __shared__ float part[BLOCK];
    part[tid] = ldexpf(v, -L * (15 - seg));   // exact pow2; uflow->0 = true decay
    __syncthreads();
    if (tid < 16) {
        float s = 0.0f;
#pragma unroll
        for (int k = 0; k < 16; ++k)          // ascending seg = ascending magnitude
            s += part[k * 16 + tid];
        ws[tensor * N + colbase + tid] = s;
    }
    if (seg == 15)
        ws[2 * N + tensor * N + col] = tmp[L - 1];   // last spike row
}

// Generic fallback (any T, N): one thread per column, sequential scan.
__global__ __launch_bounds__(BLOCK) void stdp_traces_gen(
    const float* __restrict__ pre, const float* __restrict__ post,
    float* __restrict__ ws, int N, int T)
{
    const int gid = blockIdx.x * BLOCK + threadIdx.x;
    if (gid >= 2 * N) return;
    const float* __restrict__ src = (gid < N) ? pre : post;
    const int c = (gid < N) ? gid : gid - N;
    float v = 0.0f, last = 0.0f;
    for (int t = 0; t < T; ++t) {
        const float s = src[(size_t)t * N + c];
        v += (s - v) * 0.5f;
        last = s;
    }
    ws[gid] = v;
    ws[2 * N + gid] = last;
}

// out[i][j] = x_i*q_j - p_i*y_j. Grid = N/R blocks, R=8 rows each;
// each thread: one float4 of y/q reused across 8 rows, 8 float4 stores.
__global__ __launch_bounds__(BLOCK) void stdp_outer(
    const float* __restrict__ ws, float* __restrict__ out, int N, int R)
{
    const int i0 = blockIdx.x * R;
    for (int j0 = threadIdx.x * 4; j0 < N; j0 += BLOCK * 4) {
        const float4 y4 = *reinterpret_cast<const float4*>(ws + N + j0);
        const float4 q4 = *reinterpret_cast<const float4*>(ws + 3 * N + j0);
        for (int r = 0; r < R; ++r) {
            const int i = i0 + r;
            if (i >= N) break;
            const float x_i = ws[i];
            const float p_i = ws[2 * N + i];
            float4 o;
            o.x = x_i * q4.x - p_i * y4.x;
            o.y = x_i * q4.y - p_i * y4.y;
            o.z = x_i * q4.z - p_i * y4.z;
            o.w = x_i * q4.w - p_i * y4.w;
            *reinterpret_cast<float4*>(out + (size_t)i * N + j0) = o;
        }
    }
}

extern "C" void kernel_launch(void* const* d_in, const int* in_sizes, int n_in,
                              void* d_out, int out_size, void* d_ws, size_t ws_size,
                              hipStream_t stream)
{
    // in0 = T*N_pre, in1 = T*N_post, out = N_pre*N_post => T = sqrt(in0*in1/out)
    const double t_d = sqrt((double)in_sizes[0] * (double)in_sizes[1] / (double)out_size);
    const int T = (int)(t_d + 0.5);
    const int N = in_sizes[0] / T;

    const float* pre  = (const float*)d_in[0];
    const float* post = (const float*)d_in[1];
    float* out = (float*)d_out;
    float* ws  = (float*)d_ws;                 // needs 4N floats = 16 KB

    if (T % 16 == 0 && (T >> 4) <= 16 && N % 16 == 0) {
        stdp_traces16<<<2 * (N >> 4), BLOCK, 0, stream>>>(pre, post, ws, N, T);
    } else {
        stdp_traces_gen<<<(2 * N + BLOCK - 1) / BLOCK, BLOCK, 0, stream>>>(pre, post, ws, N, T);
    }
    const int R = 8;
    stdp_outer<<<(N + R - 1) / R, BLOCK, 0, stream>>>(ws, out, N, R);
}